// Round 4
// baseline (140.803 us; speedup 1.0000x reference)
//
#include <hip/hip_runtime.h>
#include <math.h>

// HAKE scoring for MI355X — round 4: two-kernel restructure.
// R3 lesson: broadcast ds_read_b128 (16 useful B / ~14 cyc) + 6 VALU/triple
// made LDS-pipe (~29us/CU) and VALU (~36us) co-limiting at 38% occupancy.
// Now: r-term = one K=768 bf16 MFMA GEMM (K1, R into d_out as scratch);
// phase term elementwise with 3 ops/triple, pt-only LDS, 100% occupancy (K2).

#define B_      32
#define D_      256
#define N_      20000
#define NT      8
#define NBLK2   (N_ / NT)        // 2500
#define NBLK1   (N_ / 32)        // 625

// x/(EMB_RANGE/PI)/2 in revolutions = x/(4*EMB_RANGE)
#define K2S 4.571428571428571f

typedef short  short8 __attribute__((ext_vector_type(8)));
typedef float  f32x16 __attribute__((ext_vector_type(16)));

__device__ __forceinline__ float sinrev_(float x) { return __builtin_amdgcn_sinf(x); }

__device__ __forceinline__ short bf16r(float x) {
    union { float f; unsigned u; } v; v.f = x;
    unsigned r = (v.u + 0x7FFFu + ((v.u >> 16) & 1u)) >> 16;
    return (short)r;
}

// ---------------------------------------------------------------------------
// K1: R[b,n] = sum_d (mh' - mt*cc)^2 via one 32x20000x768 bf16 MFMA GEMM.
//   k in [0,256):   A=cc^2        B=mt^2
//   k in [256,512): A=-2*mh'*cc   B=mt
//   k in [512,768): A=mh'^2       B=1
// grid 625 x 256thr; 4 waves split K (192 each = 12 MFMA steps); R -> d_out.
// ---------------------------------------------------------------------------
__global__ void hake_rgemm(const int* __restrict__ e1, const int* __restrict__ rel,
                           const float* __restrict__ emb_e, const float* __restrict__ emb_rel,
                           float* __restrict__ R)
{
    __shared__ float cred[4][64][16];   // 16 KB cross-wave reduce

    const int t    = threadIdx.x;
    const int lane = t & 63;
    const int w    = t >> 6;
    const int n0   = blockIdx.x * 32;
    const int b    = lane & 31;
    const int h    = lane >> 5;
    const int nn   = n0 + b;            // col for B side

    const int he = e1[b];
    const int hr = rel[b];
    const float* mhp = emb_e  + (size_t)he * (2 * D_) + D_;
    const float* mrp = emb_rel + (size_t)hr * (3 * D_) + D_;
    const float* bip = emb_rel + (size_t)hr * (3 * D_) + 2 * D_;
    const float* mtp = emb_e  + (size_t)nn * (2 * D_) + D_;

    f32x16 c;
#pragma unroll
    for (int r = 0; r < 16; ++r) c[r] = 0.0f;

#pragma unroll
    for (int s = 0; s < 12; ++s) {
        const int kb   = w * 192 + s * 16;      // wave-uniform
        const int term = kb >> 8;               // 0,1,2
        const int d    = (kb & 255) + h * 8;    // 8 consecutive d

        float av[8], bv[8];
#pragma unroll
        for (int i = 0; i < 8; ++i) {
            float mr = fabsf(mrp[d + i]);
            float bi = fminf(bip[d + i], 1.0f);
            bi = (bi < -mr) ? -mr : bi;
            float cc = 1.0f - bi;
            if (term == 0) {
                float mt = mtp[d + i];
                av[i] = cc * cc;  bv[i] = mt * mt;
            } else if (term == 1) {
                float mh = mhp[d + i] * (mr + bi);
                av[i] = -2.0f * mh * cc;  bv[i] = mtp[d + i];
            } else {
                float mh = mhp[d + i] * (mr + bi);
                av[i] = mh * mh;  bv[i] = 1.0f;
            }
        }
        short8 af, bf;
#pragma unroll
        for (int i = 0; i < 8; ++i) { af[i] = bf16r(av[i]); bf[i] = bf16r(bv[i]); }
        c = __builtin_amdgcn_mfma_f32_32x32x16_bf16(af, bf, c, 0, 0, 0);
    }

#pragma unroll
    for (int r = 0; r < 16; ++r) cred[w][lane][r] = c[r];
    __syncthreads();

    for (int sl = t; sl < 1024; sl += 256) {
        const int ln = sl >> 4, r = sl & 15;
        float sum = cred[0][ln][r] + cred[1][ln][r] + cred[2][ln][r] + cred[3][ln][r];
        const int col = ln & 31;
        const int row = (r & 3) + 8 * (r >> 2) + 4 * (ln >> 5);   // verified C/D map
        R[(size_t)row * N_ + n0 + col] = sum;
    }
}

// ---------------------------------------------------------------------------
// K2: phase term + finalize. grid 2500 x 512thr; thread (b=t&31, g=t>>5) owns
// d-slice of 16; LDS = pre-scaled phase_tail only (8 rows x 256 f32 = 8KB).
// Inner: 3 VALU slots/triple (sub, v_sin, add|abs|). Reads R from d_out,
// overwrites with sigmoid.
// ---------------------------------------------------------------------------
__global__ __launch_bounds__(512, 8)
void hake_phase(const int* __restrict__ e1, const int* __restrict__ rel,
                const float* __restrict__ emb_e, const float* __restrict__ emb_rel,
                const float* __restrict__ pw_p, const float* __restrict__ mw_p,
                float* __restrict__ out)
{
    __shared__ float4 ptl[NT][D_ / 4];     // 8 KB: pre-scaled phase_tail
    __shared__ float  red[8][NT][32];      // 8 KB: per-wave sph partials

    const int t    = threadIdx.x;
    const int lane = t & 63;
    const int w    = t >> 6;               // wave 0..7
    const int b    = t & 31;
    const int g    = t >> 5;               // d-group 0..15
    const int d_lo = g * 16;

    const int n0 = blockIdx.x * NT;

    // stage: wave w stages phase-half of row n0+w (coalesced float4)
    const float* rowp = emb_e + (size_t)(n0 + w) * (2 * D_);
    float4 pv = *(const float4*)(rowp + lane * 4);

    // table: ar[i] = (phase_head + phase_rel)*K2S for d in [d_lo, d_lo+16)
    float ar[16];
    {
        const int he = e1[b];
        const int hr = rel[b];
        const float* be = emb_e + (size_t)he * (2 * D_);
        const float* br = emb_rel + (size_t)hr * (3 * D_);
#pragma unroll
        for (int ii = 0; ii < 4; ++ii) {
            float4 ph4 = *(const float4*)(be + d_lo + ii * 4);
            float4 pr4 = *(const float4*)(br + d_lo + ii * 4);
            ar[ii * 4 + 0] = (ph4.x + pr4.x) * K2S;
            ar[ii * 4 + 1] = (ph4.y + pr4.y) * K2S;
            ar[ii * 4 + 2] = (ph4.z + pr4.z) * K2S;
            ar[ii * 4 + 3] = (ph4.w + pr4.w) * K2S;
        }
    }

    ptl[w][lane] = make_float4(pv.x * K2S, pv.y * K2S, pv.z * K2S, pv.w * K2S);
    __syncthreads();

    float sph[NT];
#pragma unroll
    for (int j = 0; j < NT; ++j) sph[j] = 0.0f;

    const int q0 = d_lo >> 2;
#pragma unroll
    for (int q = 0; q < 4; ++q) {
#pragma unroll
        for (int j = 0; j < NT; ++j) {
            float4 tv = ptl[j][q0 + q];            // broadcast in 32-lane group
            sph[j] += fabsf(sinrev_(ar[q * 4 + 0] - tv.x));
            sph[j] += fabsf(sinrev_(ar[q * 4 + 1] - tv.y));
            sph[j] += fabsf(sinrev_(ar[q * 4 + 2] - tv.z));
            sph[j] += fabsf(sinrev_(ar[q * 4 + 3] - tv.w));
        }
    }

#pragma unroll
    for (int j = 0; j < NT; ++j) sph[j] += __shfl_xor(sph[j], 32, 64);
    if (lane < 32) {
#pragma unroll
        for (int j = 0; j < NT; ++j) red[w][j][lane] = sph[j];
    }
    __syncthreads();

    if (t < 256) {
        const int j  = t & 7;
        const int bb = t >> 3;
        float pa = 0.0f;
#pragma unroll
        for (int ww = 0; ww < 8; ++ww) pa += red[ww][j][bb];
        const size_t idx = (size_t)bb * N_ + (n0 + j);
        float rr = out[idx];                       // R from K1 (d_out scratch)
        rr = fmaxf(rr, 0.0f);                      // guard bf16 rounding
        float z = fmaf(pa, pw_p[0], sqrtf(rr) * mw_p[0]) - 12.0f;   // GAMMA
        out[idx] = 1.0f / (1.0f + __expf(z));
    }
}

extern "C" void kernel_launch(void* const* d_in, const int* in_sizes, int n_in,
                              void* d_out, int out_size, void* d_ws, size_t ws_size,
                              hipStream_t stream)
{
    // inputs: 0:g 1:e1 2:rel 3:e2_multi(unused) 4:emb_e 5:emb_rel 6:phase_w 7:mod_w
    const int*   e1      = (const int*)d_in[1];
    const int*   rel     = (const int*)d_in[2];
    const float* emb_e   = (const float*)d_in[4];
    const float* emb_rel = (const float*)d_in[5];
    const float* pw      = (const float*)d_in[6];
    const float* mw      = (const float*)d_in[7];
    float* out = (float*)d_out;

    hipLaunchKernelGGL(hake_rgemm, dim3(NBLK1), dim3(256), 0, stream,
                       e1, rel, emb_e, emb_rel, out);
    hipLaunchKernelGGL(hake_phase, dim3(NBLK2), dim3(512), 0, stream,
                       e1, rel, emb_e, emb_rel, pw, mw, out);
}

// Round 5
// 44.805 us; speedup vs baseline: 3.1426x; 3.1426x over previous
//
#include <hip/hip_runtime.h>
#include <math.h>

// HAKE scoring for MI355X — round 5.
// R4 lesson: K1 (r-term GEMM) at 115us was latency-starved: 625 blocks,
// scalar uncoalesced mt gathers, A recomputed per step. Rewrite: per-block
// A1/A2/S0 built once in LDS, waves stream mt coalesced (read-once chip-wide),
// 32 chained 16x16x32 bf16 MFMAs per wave. K2 (phase, ~25us) unchanged except
// early R prefetch.

#define D_      256
#define N_      20000
#define NT      8
#define NBLK2   (N_ / NT)          // 2500
#define K1TILE  64
#define NBLK1   ((N_ + K1TILE - 1) / K1TILE)   // 313 (last block: 2 waves idle)
#define APITCH  264                // bf16 elems per A row (256 + 8 pad)

// x/(EMB_RANGE/PI)/2 in revolutions = x/(4*EMB_RANGE)
#define K2S 4.571428571428571f

typedef short short8 __attribute__((ext_vector_type(8)));
typedef float f32x4  __attribute__((ext_vector_type(4)));

__device__ __forceinline__ float sinrev_(float x) { return __builtin_amdgcn_sinf(x); }

__device__ __forceinline__ short bf16r(float x) {
    union { float f; unsigned u; } v; v.f = x;
    unsigned r = (v.u + 0x7FFFu + ((v.u >> 16) & 1u)) >> 16;
    return (short)r;
}

// ---------------------------------------------------------------------------
// K1: R[b,n] = S0_b + sum_d cc^2*mt^2 - 2*sum_d (mh'cc)*mt   (K=256 each)
// grid 313 x 256thr (4 waves). Phase 1: build A1=cc^2, A2=-2mh'cc (bf16,
// padded LDS) + S0_b. Phase 2: wave w -> 16-col tile; 8 K-chunks x
// (2 terms x 2 M-tiles) chained MFMAs; mt loaded coalesced, once chip-wide.
// ---------------------------------------------------------------------------
__global__ __launch_bounds__(256)
void hake_rgemm(const int* __restrict__ e1, const int* __restrict__ rel,
                const float* __restrict__ emb_e, const float* __restrict__ emb_rel,
                float* __restrict__ R)
{
    __shared__ short A1[32 * APITCH];   // cc^2        (~16.5 KB)
    __shared__ short A2[32 * APITCH];   // -2*mh'*cc   (~16.5 KB)
    __shared__ float S0p[8][32];
    __shared__ float S0[32];

    const int t = threadIdx.x;

    // ---- phase 1: A tables + S0 --------------------------------------------
    {
        const int b  = t & 31;
        const int dg = t >> 5;          // 8 groups x 32 d
        const int d0 = dg * 32;
        const int he = e1[b], hr = rel[b];
        const float* mhp = emb_e  + (size_t)he * (2 * D_) + D_ + d0;
        const float* mrp = emb_rel + (size_t)hr * (3 * D_) + D_ + d0;
        const float* bip = emb_rel + (size_t)hr * (3 * D_) + 2 * D_ + d0;
        float s0 = 0.0f;
#pragma unroll
        for (int q = 0; q < 8; ++q) {
            float4 mh4 = *(const float4*)(mhp + q * 4);
            float4 mr4 = *(const float4*)(mrp + q * 4);
            float4 bi4 = *(const float4*)(bip + q * 4);
            float mhv[4] = {mh4.x, mh4.y, mh4.z, mh4.w};
            float mrv[4] = {mr4.x, mr4.y, mr4.z, mr4.w};
            float biv[4] = {bi4.x, bi4.y, bi4.z, bi4.w};
#pragma unroll
            for (int k = 0; k < 4; ++k) {
                float mr = fabsf(mrv[k]);
                float bi = fminf(biv[k], 1.0f);
                bi = (bi < -mr) ? -mr : bi;
                float cc = 1.0f - bi;
                float mh = mhv[k] * (mr + bi);
                A1[b * APITCH + d0 + q * 4 + k] = bf16r(cc * cc);
                A2[b * APITCH + d0 + q * 4 + k] = bf16r(-2.0f * mh * cc);
                s0 = fmaf(mh, mh, s0);
            }
        }
        S0p[dg][b] = s0;
    }
    __syncthreads();
    if (t < 32) {
        float s = 0.0f;
#pragma unroll
        for (int q = 0; q < 8; ++q) s += S0p[q][t];
        S0[t] = s;
    }
    __syncthreads();

    // ---- phase 2: per-wave 16-col GEMM tile --------------------------------
    const int w = t >> 6, l = t & 63;
    const int n0 = blockIdx.x * K1TILE + w * 16;
    if (n0 < N_) {                       // wave-uniform guard (20000 % 16 == 0)
        const int fr   = l & 15;         // row/col within 16x16 tile
        const int koff = (l >> 4) * 8;   // k sub-range owned by this lane
        const float* mtp = emb_e + (size_t)(n0 + fr) * (2 * D_) + D_;

        f32x4 acc0 = {0.f, 0.f, 0.f, 0.f};
        f32x4 acc1 = {0.f, 0.f, 0.f, 0.f};
#pragma unroll
        for (int ch = 0; ch < 8; ++ch) {
            const int d = ch * 32 + koff;
            float4 va = *(const float4*)(mtp + d);
            float4 vb = *(const float4*)(mtp + d + 4);
            float v[8] = {va.x, va.y, va.z, va.w, vb.x, vb.y, vb.z, vb.w};
            short8 b1f, b2f;
#pragma unroll
            for (int i = 0; i < 8; ++i) {
                b2f[i] = bf16r(v[i]);
                b1f[i] = bf16r(v[i] * v[i]);
            }
            short8 a1_0 = *(const short8*)(&A1[fr * APITCH + d]);
            short8 a2_0 = *(const short8*)(&A2[fr * APITCH + d]);
            short8 a1_1 = *(const short8*)(&A1[(16 + fr) * APITCH + d]);
            short8 a2_1 = *(const short8*)(&A2[(16 + fr) * APITCH + d]);
            acc0 = __builtin_amdgcn_mfma_f32_16x16x32_bf16(a1_0, b1f, acc0, 0, 0, 0);
            acc0 = __builtin_amdgcn_mfma_f32_16x16x32_bf16(a2_0, b2f, acc0, 0, 0, 0);
            acc1 = __builtin_amdgcn_mfma_f32_16x16x32_bf16(a1_1, b1f, acc1, 0, 0, 0);
            acc1 = __builtin_amdgcn_mfma_f32_16x16x32_bf16(a2_1, b2f, acc1, 0, 0, 0);
        }

        // C/D map (m89-verified): col = lane&15, row = (lane>>4)*4 + reg
#pragma unroll
        for (int r = 0; r < 4; ++r) {
            const int row = (l >> 4) * 4 + r;
            R[(size_t)row * N_ + n0 + fr]        = acc0[r] + S0[row];
            R[(size_t)(16 + row) * N_ + n0 + fr] = acc1[r] + S0[16 + row];
        }
    }
}

// ---------------------------------------------------------------------------
// K2: phase term + finalize (structure from R4, + early R prefetch).
// grid 2500 x 512thr; thread (b=t&31, g=t>>5) owns 16 d; LDS = pre-scaled
// phase_tail (8 KB). 3 VALU slots/triple. Reads R from d_out, overwrites.
// ---------------------------------------------------------------------------
__global__ __launch_bounds__(512, 8)
void hake_phase(const int* __restrict__ e1, const int* __restrict__ rel,
                const float* __restrict__ emb_e, const float* __restrict__ emb_rel,
                const float* __restrict__ pw_p, const float* __restrict__ mw_p,
                float* __restrict__ out)
{
    __shared__ float4 ptl[NT][D_ / 4];     // 8 KB: pre-scaled phase_tail
    __shared__ float  red[8][NT][32];      // 8 KB: per-wave sph partials

    const int t    = threadIdx.x;
    const int lane = t & 63;
    const int w    = t >> 6;               // wave 0..7
    const int b    = t & 31;
    const int g    = t >> 5;               // d-group 0..15
    const int d_lo = g * 16;

    const int n0 = blockIdx.x * NT;

    // early prefetch of R (hides HBM latency under the compute below)
    const int jj = t & 7, bb = t >> 3;
    const size_t oidx = (size_t)bb * N_ + (n0 + jj);
    float rr = 0.0f;
    if (t < 256) rr = out[oidx];

    // stage: wave w stages phase-half of row n0+w (coalesced float4)
    const float* rowp = emb_e + (size_t)(n0 + w) * (2 * D_);
    float4 pv = *(const float4*)(rowp + lane * 4);

    // table: ar[i] = (phase_head + phase_rel)*K2S for d in [d_lo, d_lo+16)
    float ar[16];
    {
        const int he = e1[b];
        const int hr = rel[b];
        const float* be = emb_e + (size_t)he * (2 * D_);
        const float* br = emb_rel + (size_t)hr * (3 * D_);
#pragma unroll
        for (int ii = 0; ii < 4; ++ii) {
            float4 ph4 = *(const float4*)(be + d_lo + ii * 4);
            float4 pr4 = *(const float4*)(br + d_lo + ii * 4);
            ar[ii * 4 + 0] = (ph4.x + pr4.x) * K2S;
            ar[ii * 4 + 1] = (ph4.y + pr4.y) * K2S;
            ar[ii * 4 + 2] = (ph4.z + pr4.z) * K2S;
            ar[ii * 4 + 3] = (ph4.w + pr4.w) * K2S;
        }
    }

    ptl[w][lane] = make_float4(pv.x * K2S, pv.y * K2S, pv.z * K2S, pv.w * K2S);
    __syncthreads();

    float sph[NT];
#pragma unroll
    for (int j = 0; j < NT; ++j) sph[j] = 0.0f;

    const int q0 = d_lo >> 2;
#pragma unroll
    for (int q = 0; q < 4; ++q) {
#pragma unroll
        for (int j = 0; j < NT; ++j) {
            float4 tv = ptl[j][q0 + q];            // broadcast in 32-lane group
            sph[j] += fabsf(sinrev_(ar[q * 4 + 0] - tv.x));
            sph[j] += fabsf(sinrev_(ar[q * 4 + 1] - tv.y));
            sph[j] += fabsf(sinrev_(ar[q * 4 + 2] - tv.z));
            sph[j] += fabsf(sinrev_(ar[q * 4 + 3] - tv.w));
        }
    }

#pragma unroll
    for (int j = 0; j < NT; ++j) sph[j] += __shfl_xor(sph[j], 32, 64);
    if (lane < 32) {
#pragma unroll
        for (int j = 0; j < NT; ++j) red[w][j][lane] = sph[j];
    }
    __syncthreads();

    if (t < 256) {
        float pa = 0.0f;
#pragma unroll
        for (int ww = 0; ww < 8; ++ww) pa += red[ww][jj][bb];
        float rrc = fmaxf(rr, 0.0f);               // guard bf16 rounding
        float z = fmaf(pa, pw_p[0], sqrtf(rrc) * mw_p[0]) - 12.0f;   // GAMMA
        out[oidx] = 1.0f / (1.0f + __expf(z));
    }
}

extern "C" void kernel_launch(void* const* d_in, const int* in_sizes, int n_in,
                              void* d_out, int out_size, void* d_ws, size_t ws_size,
                              hipStream_t stream)
{
    // inputs: 0:g 1:e1 2:rel 3:e2_multi(unused) 4:emb_e 5:emb_rel 6:phase_w 7:mod_w
    const int*   e1      = (const int*)d_in[1];
    const int*   rel     = (const int*)d_in[2];
    const float* emb_e   = (const float*)d_in[4];
    const float* emb_rel = (const float*)d_in[5];
    const float* pw      = (const float*)d_in[6];
    const float* mw      = (const float*)d_in[7];
    float* out = (float*)d_out;

    hipLaunchKernelGGL(hake_rgemm, dim3(NBLK1), dim3(256), 0, stream,
                       e1, rel, emb_e, emb_rel, out);
    hipLaunchKernelGGL(hake_phase, dim3(NBLK2), dim3(512), 0, stream,
                       e1, rel, emb_e, emb_rel, pw, mw, out);
}

// Round 6
// 41.994 us; speedup vs baseline: 3.3530x; 1.0670x over previous
//
#include <hip/hip_runtime.h>
#include <math.h>

// HAKE scoring for MI355X — round 6: single fused kernel.
// R5 lesson: two-kernel split pays K1 launch + serial gap + R round-trip
// through HBM; K2's analytic floor is ~13-17us (sin-pipe). Fuse: per block
// (16 tail rows), build A1/A2/S0 once (R5-verified bf16 GEMM decomposition),
// 8 waves k-split the 32x16x512 r-GEMM (4 MFMA/wave, B from direct mt
// gathers), then the 3-op/triple phase loop, one finalize. LDS ~69KB ->
// 2 blocks/CU.

#define D_   256
#define N_   20000
#define NT   16
#define NBLK (N_ / NT)      // 1250
#define AP   264            // bf16 pitch: 528B row stride -> 2-way-free banks

// x/(EMB_RANGE/PI)/2 in revolutions = x/(4*EMB_RANGE)
#define K2S 4.571428571428571f

typedef short short8 __attribute__((ext_vector_type(8)));
typedef float f32x4  __attribute__((ext_vector_type(4)));

__device__ __forceinline__ float sinrev_(float x) { return __builtin_amdgcn_sinf(x); }

__device__ __forceinline__ short bf16r(float x) {
    union { float f; unsigned u; } v; v.f = x;
    unsigned r = (v.u + 0x7FFFu + ((v.u >> 16) & 1u)) >> 16;
    return (short)r;
}

__device__ __forceinline__ short8 pack8(float4 a, float4 b, bool sq) {
    float v[8] = {a.x, a.y, a.z, a.w, b.x, b.y, b.z, b.w};
    short8 r;
#pragma unroll
    for (int i = 0; i < 8; ++i) { float x = sq ? v[i] * v[i] : v[i]; r[i] = bf16r(x); }
    return r;
}

__global__ __launch_bounds__(512, 4)
void hake_fused(const int* __restrict__ e1, const int* __restrict__ rel,
                const float* __restrict__ emb_e, const float* __restrict__ emb_rel,
                const float* __restrict__ pw_p, const float* __restrict__ mw_p,
                float* __restrict__ out)
{
    __shared__ short  A1[32 * AP];          // cc^2        16.9 KB
    __shared__ short  A2[32 * AP];          // -2*mh'*cc   16.9 KB
    __shared__ float4 P[NT][64];            // scaled phase_tail 16 KB
    __shared__ float  redr[8][32][17];      // r partials 17.4 KB (reused for phase red)
    __shared__ float  S0p[16][32];
    __shared__ float  S0[32];

    const int t  = threadIdx.x;
    const int l  = t & 63;
    const int w  = t >> 6;        // wave 0..7
    const int b  = t & 31;
    const int g  = t >> 5;        // d-group 0..15 (16 d each)
    const int d0 = g * 16;
    const int fr = l & 15;
    const int hi = l >> 4;
    const int n0 = blockIdx.x * NT;

    // ---- B prefetch: wave w -> term (w>>2), d-slice (w&3)*64 ---------------
    const int term  = w >> 2;
    const int dbase = (w & 3) * 64;
    const float* mtp = emb_e + (size_t)(n0 + fr) * (2 * D_) + D_;
    float4 bva0 = *(const float4*)(mtp + dbase + hi * 8);
    float4 bvb0 = *(const float4*)(mtp + dbase + hi * 8 + 4);
    float4 bva1 = *(const float4*)(mtp + dbase + 32 + hi * 8);
    float4 bvb1 = *(const float4*)(mtp + dbase + 32 + hi * 8 + 4);

    // ---- P stage loads: wave w stages rows 2w, 2w+1 (full 64-lane rows) ----
    const float* prow0 = emb_e + (size_t)(n0 + w * 2) * (2 * D_);
    const float* prow1 = emb_e + (size_t)(n0 + w * 2 + 1) * (2 * D_);
    float4 pv0 = *(const float4*)(prow0 + l * 4);
    float4 pv1 = *(const float4*)(prow1 + l * 4);

    // ---- head/rel tables: ar (regs), A1/A2 (LDS), S0 partial ---------------
    float ar[16];
    {
        const int he = e1[b], hr = rel[b];
        const float* be = emb_e  + (size_t)he * (2 * D_);
        const float* br = emb_rel + (size_t)hr * (3 * D_);
        float a1v[16], a2v[16];
        float s0 = 0.0f;
#pragma unroll
        for (int q = 0; q < 4; ++q) {
            float4 ph4 = *(const float4*)(be + d0 + q * 4);
            float4 pq4 = *(const float4*)(br + d0 + q * 4);
            float4 mh4 = *(const float4*)(be + D_ + d0 + q * 4);
            float4 mr4 = *(const float4*)(br + D_ + d0 + q * 4);
            float4 bi4 = *(const float4*)(br + 2 * D_ + d0 + q * 4);
            float phv[4] = {ph4.x, ph4.y, ph4.z, ph4.w};
            float pqv[4] = {pq4.x, pq4.y, pq4.z, pq4.w};
            float mhv[4] = {mh4.x, mh4.y, mh4.z, mh4.w};
            float mrv[4] = {mr4.x, mr4.y, mr4.z, mr4.w};
            float biv[4] = {bi4.x, bi4.y, bi4.z, bi4.w};
#pragma unroll
            for (int k = 0; k < 4; ++k) {
                const int i = q * 4 + k;
                ar[i] = (phv[k] + pqv[k]) * K2S;
                float mr = fabsf(mrv[k]);
                float bi = fminf(biv[k], 1.0f);
                bi = (bi < -mr) ? -mr : bi;
                float cc = 1.0f - bi;
                float mh = mhv[k] * (mr + bi);
                a1v[i] = cc * cc;
                a2v[i] = -2.0f * mh * cc;
                s0 = fmaf(mh, mh, s0);
            }
        }
        short8 w1a, w1b, w2a, w2b;
#pragma unroll
        for (int i = 0; i < 8; ++i) {
            w1a[i] = bf16r(a1v[i]);     w1b[i] = bf16r(a1v[8 + i]);
            w2a[i] = bf16r(a2v[i]);     w2b[i] = bf16r(a2v[8 + i]);
        }
        *(short8*)(&A1[b * AP + d0])     = w1a;
        *(short8*)(&A1[b * AP + d0 + 8]) = w1b;
        *(short8*)(&A2[b * AP + d0])     = w2a;
        *(short8*)(&A2[b * AP + d0 + 8]) = w2b;
        S0p[g][b] = s0;
    }
    P[w * 2][l]     = make_float4(pv0.x * K2S, pv0.y * K2S, pv0.z * K2S, pv0.w * K2S);
    P[w * 2 + 1][l] = make_float4(pv1.x * K2S, pv1.y * K2S, pv1.z * K2S, pv1.w * K2S);
    __syncthreads();

    if (t < 32) {
        float s = 0.0f;
#pragma unroll
        for (int q = 0; q < 16; ++q) s += S0p[q][t];
        S0[t] = s;
    }

    // ---- r-term MFMAs: 2 m-tiles x 2 k-steps per wave ----------------------
    {
        short8 bf0 = pack8(bva0, bvb0, term == 0);
        short8 bf1 = pack8(bva1, bvb1, term == 0);
        const short* At = term ? A2 : A1;
        short8 a00 = *(const short8*)(At + fr * AP + dbase + hi * 8);
        short8 a01 = *(const short8*)(At + fr * AP + dbase + 32 + hi * 8);
        short8 a10 = *(const short8*)(At + (16 + fr) * AP + dbase + hi * 8);
        short8 a11 = *(const short8*)(At + (16 + fr) * AP + dbase + 32 + hi * 8);
        f32x4 acc0 = {0.f, 0.f, 0.f, 0.f};
        f32x4 acc1 = {0.f, 0.f, 0.f, 0.f};
        acc0 = __builtin_amdgcn_mfma_f32_16x16x32_bf16(a00, bf0, acc0, 0, 0, 0);
        acc0 = __builtin_amdgcn_mfma_f32_16x16x32_bf16(a01, bf1, acc0, 0, 0, 0);
        acc1 = __builtin_amdgcn_mfma_f32_16x16x32_bf16(a10, bf0, acc1, 0, 0, 0);
        acc1 = __builtin_amdgcn_mfma_f32_16x16x32_bf16(a11, bf1, acc1, 0, 0, 0);
        // C/D map (verified): col = lane&15 (n), row = hi*4 + reg (b)
#pragma unroll
        for (int r = 0; r < 4; ++r) {
            redr[w][hi * 4 + r][fr]      = acc0[r];
            redr[w][16 + hi * 4 + r][fr] = acc1[r];
        }
    }
    __syncthreads();

    // ---- r reduce: thread t -> (b = t&31, n = t>>5) ------------------------
    const int fn = t >> 5, fb = t & 31;
    float rr = 0.0f;
#pragma unroll
    for (int ww = 0; ww < 8; ++ww) rr += redr[ww][fb][fn];
    __syncthreads();   // redr free for reuse as phase-red buffer

    // ---- phase accumulate: 16 d x 16 n per thread --------------------------
    float sph[NT];
#pragma unroll
    for (int j = 0; j < NT; ++j) sph[j] = 0.0f;
#pragma unroll
    for (int q = 0; q < 4; ++q) {
#pragma unroll
        for (int j = 0; j < NT; ++j) {
            float4 tv = P[j][g * 4 + q];      // broadcast within 32-lane group
            sph[j] += fabsf(sinrev_(ar[q * 4 + 0] - tv.x));
            sph[j] += fabsf(sinrev_(ar[q * 4 + 1] - tv.y));
            sph[j] += fabsf(sinrev_(ar[q * 4 + 2] - tv.z));
            sph[j] += fabsf(sinrev_(ar[q * 4 + 3] - tv.w));
        }
    }

    // ---- phase reduce ------------------------------------------------------
    float* redf = &redr[0][0][0];   // reused: layout [8][16][32]
#pragma unroll
    for (int j = 0; j < NT; ++j) sph[j] += __shfl_xor(sph[j], 32, 64);
    if (l < 32) {
#pragma unroll
        for (int j = 0; j < NT; ++j) redf[(w * 16 + j) * 32 + l] = sph[j];
    }
    __syncthreads();

    // ---- finalize: thread t -> (b = fb, n = n0 + fn) -----------------------
    {
        float pa = 0.0f;
#pragma unroll
        for (int ww = 0; ww < 8; ++ww) pa += redf[(ww * 16 + fn) * 32 + fb];
        float rfull = fmaxf(rr + S0[fb], 0.0f);
        float z = fmaf(pa, pw_p[0], sqrtf(rfull) * mw_p[0]) - 12.0f;  // GAMMA
        out[(size_t)fb * N_ + (n0 + fn)] = 1.0f / (1.0f + __expf(z));
    }
}

extern "C" void kernel_launch(void* const* d_in, const int* in_sizes, int n_in,
                              void* d_out, int out_size, void* d_ws, size_t ws_size,
                              hipStream_t stream)
{
    // inputs: 0:g 1:e1 2:rel 3:e2_multi(unused) 4:emb_e 5:emb_rel 6:phase_w 7:mod_w
    const int*   e1      = (const int*)d_in[1];
    const int*   rel     = (const int*)d_in[2];
    const float* emb_e   = (const float*)d_in[4];
    const float* emb_rel = (const float*)d_in[5];
    const float* pw      = (const float*)d_in[6];
    const float* mw      = (const float*)d_in[7];
    float* out = (float*)d_out;

    hipLaunchKernelGGL(hake_fused, dim3(NBLK), dim3(512), 0, stream,
                       e1, rel, emb_e, emb_rel, pw, mw, out);
}

// Round 7
// 41.763 us; speedup vs baseline: 3.3715x; 1.0055x over previous
//
#include <hip/hip_runtime.h>
#include <math.h>

// HAKE scoring for MI355X — round 7: LDS overlay for occupancy.
// R6 lesson: 70KB LDS -> 2 blocks/CU -> 4 waves/SIMD -> 48% VALUBusy,
// blocks latency-starved (per-block issue ~2us, wall ~18us). redr / P /
// phase-red are temporally disjoint -> one 17.4KB union region. 52KB ->
// 3 blocks/CU = 6 waves/SIMD. launch_bounds(512,6) (VGPR cap 85, est 72-84).

#define D_   256
#define N_   20000
#define NT   16
#define NBLK (N_ / NT)      // 1250
#define AP   264            // bf16 pitch

// x/(EMB_RANGE/PI)/2 in revolutions = x/(4*EMB_RANGE)
#define K2S 4.571428571428571f

typedef short short8 __attribute__((ext_vector_type(8)));
typedef float f32x4  __attribute__((ext_vector_type(4)));

__device__ __forceinline__ float sinrev_(float x) { return __builtin_amdgcn_sinf(x); }

__device__ __forceinline__ short bf16r(float x) {
    union { float f; unsigned u; } v; v.f = x;
    unsigned r = (v.u + 0x7FFFu + ((v.u >> 16) & 1u)) >> 16;
    return (short)r;
}

__device__ __forceinline__ short8 pack8(float4 a, float4 b, bool sq) {
    float v[8] = {a.x, a.y, a.z, a.w, b.x, b.y, b.z, b.w};
    short8 r;
#pragma unroll
    for (int i = 0; i < 8; ++i) { float x = sq ? v[i] * v[i] : v[i]; r[i] = bf16r(x); }
    return r;
}

__global__ __launch_bounds__(512, 6)
void hake_fused(const int* __restrict__ e1, const int* __restrict__ rel,
                const float* __restrict__ emb_e, const float* __restrict__ emb_rel,
                const float* __restrict__ pw_p, const float* __restrict__ mw_p,
                float* __restrict__ out)
{
    __shared__ short A1[32 * AP];        // cc^2        16.9 KB
    __shared__ short A2[32 * AP];        // -2*mh'*cc   16.9 KB
    __shared__ float U[4352];            // 17.4 KB union: redr[8][32][17] | P[16][64]f4 | redf[8][16][32]
    __shared__ float S0p[16][32];        // 2 KB
    __shared__ float S0[32];

    const int t  = threadIdx.x;
    const int l  = t & 63;
    const int w  = t >> 6;        // wave 0..7
    const int b  = t & 31;
    const int g  = t >> 5;        // d-group 0..15 (16 d each)
    const int d0 = g * 16;
    const int fr = l & 15;
    const int hi = l >> 4;
    const int n0 = blockIdx.x * NT;

    // ---- B prefetch: wave w -> term (w>>2), d-slice (w&3)*64 ---------------
    const int term  = w >> 2;
    const int dbase = (w & 3) * 64;
    const float* mtp = emb_e + (size_t)(n0 + fr) * (2 * D_) + D_;
    float4 bva0 = *(const float4*)(mtp + dbase + hi * 8);
    float4 bvb0 = *(const float4*)(mtp + dbase + hi * 8 + 4);
    float4 bva1 = *(const float4*)(mtp + dbase + 32 + hi * 8);
    float4 bvb1 = *(const float4*)(mtp + dbase + 32 + hi * 8 + 4);

    // ---- P loads into regs (LDS write deferred past r-reduce) --------------
    const float* prow0 = emb_e + (size_t)(n0 + w * 2) * (2 * D_);
    const float* prow1 = emb_e + (size_t)(n0 + w * 2 + 1) * (2 * D_);
    float4 pv0 = *(const float4*)(prow0 + l * 4);
    float4 pv1 = *(const float4*)(prow1 + l * 4);

    // ---- head/rel tables: ar (regs), A1/A2 (LDS), S0 partial ---------------
    float ar[16];
    {
        const int he = e1[b], hr = rel[b];
        const float* be = emb_e  + (size_t)he * (2 * D_);
        const float* br = emb_rel + (size_t)hr * (3 * D_);
        float a1v[16], a2v[16];
        float s0 = 0.0f;
#pragma unroll
        for (int q = 0; q < 4; ++q) {
            float4 ph4 = *(const float4*)(be + d0 + q * 4);
            float4 pq4 = *(const float4*)(br + d0 + q * 4);
            float4 mh4 = *(const float4*)(be + D_ + d0 + q * 4);
            float4 mr4 = *(const float4*)(br + D_ + d0 + q * 4);
            float4 bi4 = *(const float4*)(br + 2 * D_ + d0 + q * 4);
            float phv[4] = {ph4.x, ph4.y, ph4.z, ph4.w};
            float pqv[4] = {pq4.x, pq4.y, pq4.z, pq4.w};
            float mhv[4] = {mh4.x, mh4.y, mh4.z, mh4.w};
            float mrv[4] = {mr4.x, mr4.y, mr4.z, mr4.w};
            float biv[4] = {bi4.x, bi4.y, bi4.z, bi4.w};
#pragma unroll
            for (int k = 0; k < 4; ++k) {
                const int i = q * 4 + k;
                ar[i] = (phv[k] + pqv[k]) * K2S;
                float mr = fabsf(mrv[k]);
                float bi = fminf(biv[k], 1.0f);
                bi = (bi < -mr) ? -mr : bi;
                float cc = 1.0f - bi;
                float mh = mhv[k] * (mr + bi);
                a1v[i] = cc * cc;
                a2v[i] = -2.0f * mh * cc;
                s0 = fmaf(mh, mh, s0);
            }
        }
        short8 w1a, w1b, w2a, w2b;
#pragma unroll
        for (int i = 0; i < 8; ++i) {
            w1a[i] = bf16r(a1v[i]);     w1b[i] = bf16r(a1v[8 + i]);
            w2a[i] = bf16r(a2v[i]);     w2b[i] = bf16r(a2v[8 + i]);
        }
        *(short8*)(&A1[b * AP + d0])     = w1a;
        *(short8*)(&A1[b * AP + d0 + 8]) = w1b;
        *(short8*)(&A2[b * AP + d0])     = w2a;
        *(short8*)(&A2[b * AP + d0 + 8]) = w2b;
        S0p[g][b] = s0;
    }
    __syncthreads();                                    // b1: A + S0p ready

    if (t < 32) {
        float s = 0.0f;
#pragma unroll
        for (int q = 0; q < 16; ++q) s += S0p[q][t];
        S0[t] = s;
    }

    // ---- r-term MFMAs: 2 m-tiles x 2 k-steps per wave; partials -> U -------
    {
        short8 bf0 = pack8(bva0, bvb0, term == 0);
        short8 bf1 = pack8(bva1, bvb1, term == 0);
        const short* At = term ? A2 : A1;
        short8 a00 = *(const short8*)(At + fr * AP + dbase + hi * 8);
        short8 a01 = *(const short8*)(At + fr * AP + dbase + 32 + hi * 8);
        short8 a10 = *(const short8*)(At + (16 + fr) * AP + dbase + hi * 8);
        short8 a11 = *(const short8*)(At + (16 + fr) * AP + dbase + 32 + hi * 8);
        f32x4 acc0 = {0.f, 0.f, 0.f, 0.f};
        f32x4 acc1 = {0.f, 0.f, 0.f, 0.f};
        acc0 = __builtin_amdgcn_mfma_f32_16x16x32_bf16(a00, bf0, acc0, 0, 0, 0);
        acc0 = __builtin_amdgcn_mfma_f32_16x16x32_bf16(a01, bf1, acc0, 0, 0, 0);
        acc1 = __builtin_amdgcn_mfma_f32_16x16x32_bf16(a10, bf0, acc1, 0, 0, 0);
        acc1 = __builtin_amdgcn_mfma_f32_16x16x32_bf16(a11, bf1, acc1, 0, 0, 0);
        // C/D map (verified): col = lane&15 (n), row = hi*4 + reg (b)
#pragma unroll
        for (int r = 0; r < 4; ++r) {
            U[(w * 32 + hi * 4 + r) * 17 + fr]      = acc0[r];
            U[(w * 32 + 16 + hi * 4 + r) * 17 + fr] = acc1[r];
        }
    }
    __syncthreads();                                    // b3: redr ready

    // ---- r reduce: thread t -> (b = t&31, n = t>>5) ------------------------
    const int fn = t >> 5, fb = t & 31;
    float rr = 0.0f;
#pragma unroll
    for (int ww = 0; ww < 8; ++ww) rr += U[(ww * 32 + fb) * 17 + fn];
    __syncthreads();                                    // b4: redr consumed

    // ---- P -> LDS (union region), then phase loop --------------------------
    float4* Pp = (float4*)U;                            // P[16][64] float4
    Pp[(w * 2) * 64 + l]     = make_float4(pv0.x * K2S, pv0.y * K2S, pv0.z * K2S, pv0.w * K2S);
    Pp[(w * 2 + 1) * 64 + l] = make_float4(pv1.x * K2S, pv1.y * K2S, pv1.z * K2S, pv1.w * K2S);
    __syncthreads();                                    // b5: P ready

    float sph[NT];
#pragma unroll
    for (int j = 0; j < NT; ++j) sph[j] = 0.0f;
#pragma unroll
    for (int q = 0; q < 4; ++q) {
#pragma unroll
        for (int j = 0; j < NT; ++j) {
            float4 tv = Pp[j * 64 + g * 4 + q];         // 2-way broadcast: free
            sph[j] += fabsf(sinrev_(ar[q * 4 + 0] - tv.x));
            sph[j] += fabsf(sinrev_(ar[q * 4 + 1] - tv.y));
            sph[j] += fabsf(sinrev_(ar[q * 4 + 2] - tv.z));
            sph[j] += fabsf(sinrev_(ar[q * 4 + 3] - tv.w));
        }
    }

    // ---- phase reduce ------------------------------------------------------
#pragma unroll
    for (int j = 0; j < NT; ++j) sph[j] += __shfl_xor(sph[j], 32, 64);
    __syncthreads();                                    // b6: P consumed
    if (l < 32) {
#pragma unroll
        for (int j = 0; j < NT; ++j) U[(w * 16 + j) * 32 + l] = sph[j];
    }
    __syncthreads();                                    // b7: redf ready

    // ---- finalize: thread t -> (b = fb, n = n0 + fn) -----------------------
    {
        float pa = 0.0f;
#pragma unroll
        for (int ww = 0; ww < 8; ++ww) pa += U[(ww * 16 + fn) * 32 + fb];
        float rfull = fmaxf(rr + S0[fb], 0.0f);
        float z = fmaf(pa, pw_p[0], sqrtf(rfull) * mw_p[0]) - 12.0f;  // GAMMA
        out[(size_t)fb * N_ + (n0 + fn)] = 1.0f / (1.0f + __expf(z));
    }
}

extern "C" void kernel_launch(void* const* d_in, const int* in_sizes, int n_in,
                              void* d_out, int out_size, void* d_ws, size_t ws_size,
                              hipStream_t stream)
{
    // inputs: 0:g 1:e1 2:rel 3:e2_multi(unused) 4:emb_e 5:emb_rel 6:phase_w 7:mod_w
    const int*   e1      = (const int*)d_in[1];
    const int*   rel     = (const int*)d_in[2];
    const float* emb_e   = (const float*)d_in[4];
    const float* emb_rel = (const float*)d_in[5];
    const float* pw      = (const float*)d_in[6];
    const float* mw      = (const float*)d_in[7];
    float* out = (float*)d_out;

    hipLaunchKernelGGL(hake_fused, dim3(NBLK), dim3(512), 0, stream,
                       e1, rel, emb_e, emb_rel, pw, mw, out);
}